// Round 3
// baseline (244.707 us; speedup 1.0000x reference)
//
#include <hip/hip_runtime.h>
#include <stdint.h>

// y[b,o,w] = relu(bias[o] + sum_{i,kh} W[o,i,kh] * x[b,i,kh,w])
// bf16 MFMA GEMM: M=1024 (o), N=2048 (col=b*32+w), K=16384 (i*16+kh), split-K=8.

#define NDIM 1024
#define TK   16
#define KDIM 16384   // NDIM*TK
#define NCOL 2048    // 64 batches * 32 width

typedef unsigned short u16;
typedef u16   u16x8  __attribute__((ext_vector_type(8)));
typedef __bf16 bf16x8 __attribute__((ext_vector_type(8)));
typedef float  f32x4  __attribute__((ext_vector_type(4)));

__device__ __forceinline__ u16 f2bf(float x) {
    union { float f; unsigned u; } v; v.f = x;
    unsigned r = 0x7FFFu + ((v.u >> 16) & 1u);   // round-to-nearest-even
    return (u16)((v.u + r) >> 16);
}

// async global->LDS, 16B/lane; LDS dest is wave-uniform base + lane*16
__device__ __forceinline__ void load_lds_16B(const u16* g, u16* l) {
    __builtin_amdgcn_global_load_lds(
        (__attribute__((address_space(1))) void*)(uintptr_t)g,
        (__attribute__((address_space(3))) void*)(unsigned)(uintptr_t)l,
        16, 0, 0);
}

// ---------------------------------------------------------------------------
// Kernel 1: exact fp32 top-16 per row, one wave per row, all in registers.
// ---------------------------------------------------------------------------
__global__ __launch_bounds__(256) void topk_kernel(const float* __restrict__ f1,
                                                   int* __restrict__ idx) {
    const int lane = threadIdx.x & 63;
    const int row  = blockIdx.x * 4 + (threadIdx.x >> 6);
    float v[16];
    const float* src = f1 + row * NDIM + lane;
    #pragma unroll
    for (int j = 0; j < 16; ++j) v[j] = src[j * 64];

    for (int sel = 0; sel < TK; ++sel) {
        float best = -3.402823466e38f; int bg = 0x7fffffff;
        #pragma unroll
        for (int j = 0; j < 16; ++j) {
            if (v[j] > best) { best = v[j]; bg = j * 64 + lane; }
        }
        #pragma unroll
        for (int s = 1; s < 64; s <<= 1) {
            float ov = __shfl_xor(best, s);
            int   og = __shfl_xor(bg, s);
            if (ov > best || (ov == best && og < bg)) { best = ov; bg = og; }
        }
        if (lane == sel) idx[row * TK + sel] = bg;
        #pragma unroll
        for (int j = 0; j < 16; ++j)
            if (bg == j * 64 + lane) v[j] = -3.402823466e38f;
    }
}

// ---------------------------------------------------------------------------
// Kernel 2: conv_w fp32 -> bf16. Flat [o][i][kh] IS A[o][k], k=i*16+kh.
// ---------------------------------------------------------------------------
__global__ __launch_bounds__(256) void convw_kernel(const float* __restrict__ W,
                                                    u16* __restrict__ Wb) {
    const int tid = blockIdx.x * 256 + threadIdx.x;
    const int base = tid * 8;
    float4 a = *(const float4*)(W + base);
    float4 b = *(const float4*)(W + base + 4);
    u16x8 o;
    o[0] = f2bf(a.x); o[1] = f2bf(a.y); o[2] = f2bf(a.z); o[3] = f2bf(a.w);
    o[4] = f2bf(b.x); o[5] = f2bf(b.y); o[6] = f2bf(b.z); o[7] = f2bf(b.w);
    *(u16x8*)(Wb + base) = o;
}

// ---------------------------------------------------------------------------
// Kernel 3: build Xt[col][k] bf16, col=b*32+w, k=i*16+kh.
// Coalesced float4 reads of contiguous f1 chunks -> LDS transpose ->
// 256B-contiguous coalesced writes.
// ---------------------------------------------------------------------------
__global__ __launch_bounds__(256) void buildx_kernel(const float* __restrict__ f1,
                                                     const int* __restrict__ idx,
                                                     u16* __restrict__ Xt) {
    __shared__ u16 Ls[32 * 128];            // [w][ci*16+kh], 8KB
    const int b  = blockIdx.x >> 7;         // grid 64*128
    const int i8 = blockIdx.x & 127;
    const int t  = threadIdx.x;
    const int ci = t >> 5;                  // which of 8 i's
    const int u  = t & 31;                  // position within 512-float chunk
    const int i  = i8 * 8 + ci;
    const int q = i & 3, nl = i >> 6, tt = (i >> 2) & 15;
    const int row = (q < 2) ? (b * 16 + nl) : idx[(b * 16 + nl) * TK + tt];
    const float* src = f1 + row * NDIM + (q & 1) * 512 + u * 16;
    const int kh = u >> 1;
    const int w0 = (u & 1) * 16;
    #pragma unroll
    for (int j4 = 0; j4 < 4; ++j4) {
        float4 val = *(const float4*)(src + j4 * 4);
        Ls[(w0 + j4 * 4 + 0) * 128 + ci * 16 + kh] = f2bf(val.x);
        Ls[(w0 + j4 * 4 + 1) * 128 + ci * 16 + kh] = f2bf(val.y);
        Ls[(w0 + j4 * 4 + 2) * 128 + ci * 16 + kh] = f2bf(val.z);
        Ls[(w0 + j4 * 4 + 3) * 128 + ci * 16 + kh] = f2bf(val.w);
    }
    __syncthreads();
    const int wv = t >> 3, seg = t & 7;     // 8 threads per output row
    u16x8 a0 = *(const u16x8*)(Ls + wv * 128 + seg * 16);
    u16x8 a1 = *(const u16x8*)(Ls + wv * 128 + seg * 16 + 8);
    u16* dst = Xt + (size_t)(b * 32 + wv) * KDIM + i8 * 128 + seg * 16;
    *(u16x8*)(dst)     = a0;
    *(u16x8*)(dst + 8) = a1;
}

// ---------------------------------------------------------------------------
// Kernel 4: bf16 MFMA GEMM, 256x128 block tile, BK=64, split-K=8
// (grid 4x16x8 = 512 blocks x 512 threads = 2 blocks/CU = 16 waves/CU).
// 8 waves, each 64x64 (4x4 of 16x16x32). XOR-swizzled LDS (swizzle applied
// to the GLOBAL source chunk). Epilogue: scatter-atomic into zeroed out.
// ---------------------------------------------------------------------------
#define BM 256
#define BN 128
#define BK 64
#define ZSPLIT 8
#define KCH (KDIM / ZSPLIT)   // 2048 per split

__global__ __launch_bounds__(512, 4) void gemm_kernel(const u16* __restrict__ A,
                                                      const u16* __restrict__ B,
                                                      float* __restrict__ out) {
    __shared__ __align__(16) u16 As[BM * BK];   // 32KB, [row][chunk^(row&7)]
    __shared__ __align__(16) u16 Bs[BN * BK];   // 16KB
    const int t    = threadIdx.x;
    const int lane = t & 63;
    const int wave = t >> 6;             // 0..7
    const int wm   = (wave >> 1) * 64;   // 0,64,128,192
    const int wn   = (wave & 1) * 64;    // 0,64
    const int quad = lane >> 4;
    const int l16  = lane & 15;
    const int sw   = l16 & 7;            // == row&7 for all fragment rows
    const int o0 = blockIdx.x * BM;
    const int n0 = blockIdx.y * BN;
    const int kb = blockIdx.z * KCH;

    f32x4 acc[4][4] = {};

    // staging: slot s=c*512+t -> row=s>>3=c*64+rT, chunk c8=s&7; source chunk
    // is XOR-swizzled (c8 ^ (row&7)), row&7 == rT&7.
    const int rT = t >> 3;               // 0..63
    const int c8 = t & 7;
    const int csw = (c8 ^ (rT & 7)) * 8;
    const u16* gA = A + (size_t)(o0 + rT) * KDIM + kb + csw;
    const u16* gB = B + (size_t)(n0 + rT) * KDIM + kb + csw;
    u16* lA = As + t * 8;
    u16* lB = Bs + t * 8;

    for (int k0 = 0; k0 < KCH; k0 += BK) {
        #pragma unroll
        for (int c = 0; c < 4; ++c)
            load_lds_16B(gA + (size_t)c * 64 * KDIM + k0, lA + c * 4096);
        #pragma unroll
        for (int c = 0; c < 2; ++c)
            load_lds_16B(gB + (size_t)c * 64 * KDIM + k0, lB + c * 4096);
        __syncthreads();

        #pragma unroll
        for (int ks = 0; ks < 2; ++ks) {
            bf16x8 af[4], bfr[4];
            #pragma unroll
            for (int mt = 0; mt < 4; ++mt) {
                u16x8 bits = *(const u16x8*)(As + (wm + mt * 16 + l16) * BK
                                                + (((ks * 4 + quad) ^ sw) * 8));
                af[mt] = __builtin_bit_cast(bf16x8, bits);
            }
            #pragma unroll
            for (int nt = 0; nt < 4; ++nt) {
                u16x8 bits = *(const u16x8*)(Bs + (wn + nt * 16 + l16) * BK
                                                + (((ks * 4 + quad) ^ sw) * 8));
                bfr[nt] = __builtin_bit_cast(bf16x8, bits);
            }
            #pragma unroll
            for (int mt = 0; mt < 4; ++mt)
                #pragma unroll
                for (int nt = 0; nt < 4; ++nt)
                    acc[mt][nt] = __builtin_amdgcn_mfma_f32_16x16x32_bf16(
                        af[mt], bfr[nt], acc[mt][nt], 0, 0, 0);
        }
        __syncthreads();
    }

    // epilogue: C/D row=quad*4+reg, col=l16; atomic-accumulate at final
    // scattered position: out[(b*16+(o>>6))*2048 + (o&63)*32 + w]
    #pragma unroll
    for (int nt = 0; nt < 4; ++nt) {
        const int n = n0 + wn + nt * 16 + l16;
        const int bb = n >> 5, w = n & 31;
        #pragma unroll
        for (int mt = 0; mt < 4; ++mt) {
            #pragma unroll
            for (int r = 0; r < 4; ++r) {
                const int o = o0 + wm + mt * 16 + quad * 4 + r;
                unsafeAtomicAdd(out + (size_t)(bb * 16 + (o >> 6)) * 2048
                                    + (o & 63) * 32 + w,
                                acc[mt][nt][r]);
            }
        }
    }
}

// ---------------------------------------------------------------------------
// Kernel 5: in-place bias + relu on the accumulated output.
// ---------------------------------------------------------------------------
__global__ __launch_bounds__(256) void finalize_kernel(float* __restrict__ out,
                                                       const float* __restrict__ bias) {
    const int tid = blockIdx.x * 256 + threadIdx.x;
    const int f = tid * 4;
    const int o = ((f >> 11) & 15) * 64 + ((f & 2047) >> 5);
    const float bv = bias[o];
    float4 x = *(float4*)(out + f);
    x.x = fmaxf(x.x + bv, 0.f);
    x.y = fmaxf(x.y + bv, 0.f);
    x.z = fmaxf(x.z + bv, 0.f);
    x.w = fmaxf(x.w + bv, 0.f);
    *(float4*)(out + f) = x;
}

// ---------------------------------------------------------------------------
extern "C" void kernel_launch(void* const* d_in, const int* in_sizes, int n_in,
                              void* d_out, int out_size, void* d_ws, size_t ws_size,
                              hipStream_t stream) {
    const float* f1   = (const float*)d_in[0];   // [1024][1024]
    const float* Wc   = (const float*)d_in[1];   // [1024][1024][16][1]
    const float* bias = (const float*)d_in[2];   // [1024]
    float* out = (float*)d_out;                  // [1024][2048]

    // workspace: idx (64KB) | Wb bf16 (32MB) | Xt bf16 (64MB)  ~= 96MB
    int* idx = (int*)d_ws;
    u16* Wb  = (u16*)((char*)d_ws + 65536);
    u16* Xt  = (u16*)((char*)d_ws + 65536 + (size_t)NDIM * KDIM * 2);

    hipMemsetAsync(d_out, 0, (size_t)NDIM * NCOL * 4, stream);
    topk_kernel<<<NDIM / 4, 256, 0, stream>>>(f1, idx);
    convw_kernel<<<(NDIM * KDIM) / (8 * 256), 256, 0, stream>>>(Wc, Wb);
    buildx_kernel<<<64 * 128, 256, 0, stream>>>(f1, idx, Xt);
    gemm_kernel<<<dim3(NDIM / BM, NCOL / BN, ZSPLIT), 512, 0, stream>>>(Wb, Xt, out);
    finalize_kernel<<<(NDIM * NCOL) / (4 * 256), 256, 0, stream>>>(out, bias);
}

// Round 4
// 234.302 us; speedup vs baseline: 1.0444x; 1.0444x over previous
//
#include <hip/hip_runtime.h>
#include <stdint.h>

// y[b,o,w] = relu(bias[o] + sum_{i,kh} W[o,i,kh] * x[b,i,kh,w])
// bf16 MFMA GEMM: M=1024 (o), N=2048 (col=b*32+w), K=16384 (i*16+kh), split-K=4.

#define NDIM 1024
#define TK   16
#define KDIM 16384   // NDIM*TK
#define NCOL 2048    // 64 batches * 32 width

typedef unsigned short u16;
typedef uint32_t u32;
typedef u16   u16x8  __attribute__((ext_vector_type(8)));
typedef u32   u32x4  __attribute__((ext_vector_type(4)));
typedef __bf16 bf16x8 __attribute__((ext_vector_type(8)));
typedef float  f32x4  __attribute__((ext_vector_type(4)));

__device__ __forceinline__ u16 f2bf(float x) {
    union { float f; unsigned u; } v; v.f = x;
    unsigned r = 0x7FFFu + ((v.u >> 16) & 1u);   // round-to-nearest-even
    return (u16)((v.u + r) >> 16);
}

// async global->LDS, 16B/lane; LDS dest is wave-uniform base + lane*16
__device__ __forceinline__ void load_lds_16B(const u16* g, u16* l) {
    __builtin_amdgcn_global_load_lds(
        (__attribute__((address_space(1))) void*)(uintptr_t)g,
        (__attribute__((address_space(3))) void*)(unsigned)(uintptr_t)l,
        16, 0, 0);
}

// ---------------------------------------------------------------------------
// Kernel 1: exact fp32 top-16 per row, one wave per row, all in registers.
// ---------------------------------------------------------------------------
__global__ __launch_bounds__(256) void topk_kernel(const float* __restrict__ f1,
                                                   int* __restrict__ idx) {
    const int lane = threadIdx.x & 63;
    const int row  = blockIdx.x * 4 + (threadIdx.x >> 6);
    float v[16];
    const float* src = f1 + row * NDIM + lane;
    #pragma unroll
    for (int j = 0; j < 16; ++j) v[j] = src[j * 64];

    for (int sel = 0; sel < TK; ++sel) {
        float best = -3.402823466e38f; int bg = 0x7fffffff;
        #pragma unroll
        for (int j = 0; j < 16; ++j) {
            if (v[j] > best) { best = v[j]; bg = j * 64 + lane; }
        }
        #pragma unroll
        for (int s = 1; s < 64; s <<= 1) {
            float ov = __shfl_xor(best, s);
            int   og = __shfl_xor(bg, s);
            if (ov > best || (ov == best && og < bg)) { best = ov; bg = og; }
        }
        if (lane == sel) idx[row * TK + sel] = bg;
        #pragma unroll
        for (int j = 0; j < 16; ++j)
            if (bg == j * 64 + lane) v[j] = -3.402823466e38f;
    }
}

// ---------------------------------------------------------------------------
// Kernel 2: conv_w fp32 -> bf16. Flat [o][i][kh] IS A[o][k], k=i*16+kh.
// ---------------------------------------------------------------------------
__global__ __launch_bounds__(256) void convw_kernel(const float* __restrict__ W,
                                                    u16* __restrict__ Wb) {
    const int tid = blockIdx.x * 256 + threadIdx.x;
    const int base = tid * 8;
    float4 a = *(const float4*)(W + base);
    float4 b = *(const float4*)(W + base + 4);
    u16x8 o;
    o[0] = f2bf(a.x); o[1] = f2bf(a.y); o[2] = f2bf(a.z); o[3] = f2bf(a.w);
    o[4] = f2bf(b.x); o[5] = f2bf(b.y); o[6] = f2bf(b.z); o[7] = f2bf(b.w);
    *(u16x8*)(Wb + base) = o;
}

// ---------------------------------------------------------------------------
// Kernel 3 (v2): build Xt[col][k] bf16, col=b*32+w, k=i*16+kh.
// Thread owns (ci, khp, wq): reads kh=2*khp and kh=2*khp+1 rows (4x float4,
// coalesced), packs (kh,kh+1) bf16 pairs into u32, 8x ds_write_b32 with
// col ^= (w & 24) bank swizzle (2-way = free). Read: 2x ds_read_b128 per
// thread at XORed seg -> 32B contiguous k-runs -> coalesced global stores.
// ---------------------------------------------------------------------------
__global__ __launch_bounds__(256) void buildx_kernel(const float* __restrict__ f1,
                                                     const int* __restrict__ idx,
                                                     u16* __restrict__ Xt) {
    __shared__ u32 Ls[32 * 64];             // [w][(ci*8+khp) ^ (w&24)], 8KB
    const int b  = blockIdx.x >> 7;         // grid 64*128
    const int i8 = blockIdx.x & 127;
    const int t  = threadIdx.x;
    const int ci  = t >> 5;                 // 0..7: which i
    const int s   = t & 31;
    const int khp = s >> 2;                 // 0..7: kh pair (2*khp, 2*khp+1)
    const int wq  = s & 3;                  // 0..3: w block of 8
    const int i  = i8 * 8 + ci;
    const int q = i & 3, nl = i >> 6, tt = (i >> 2) & 15;
    const int row = (q < 2) ? (b * 16 + nl) : idx[(b * 16 + nl) * TK + tt];
    const float* src = f1 + row * NDIM + (q & 1) * 512;
    const int base0 = khp * 64 + wq * 8;    // kh=2*khp row, w=wq*8
    float4 a0 = *(const float4*)(src + base0);
    float4 a1 = *(const float4*)(src + base0 + 4);
    float4 b0 = *(const float4*)(src + base0 + 32);   // kh+1 row
    float4 b1 = *(const float4*)(src + base0 + 36);
    float lo[8] = {a0.x, a0.y, a0.z, a0.w, a1.x, a1.y, a1.z, a1.w};
    float hi[8] = {b0.x, b0.y, b0.z, b0.w, b1.x, b1.y, b1.z, b1.w};
    const int colsw = (ci * 8 + khp) ^ (wq << 3);     // w&24 == wq<<3
    #pragma unroll
    for (int j = 0; j < 8; ++j) {
        const int w = wq * 8 + j;
        u32 p = (u32)f2bf(lo[j]) | ((u32)f2bf(hi[j]) << 16);
        Ls[w * 64 + colsw] = p;
    }
    __syncthreads();
    const int wv = t >> 3, seg = t & 7;     // output row wv, k-chunk seg*16
    const int swz = wv & 24;                // XOR key for this row (bits 3-4)
    u32x4 r0 = *(const u32x4*)(Ls + wv * 64 + ((seg * 8 + 0) ^ swz));
    u32x4 r1 = *(const u32x4*)(Ls + wv * 64 + ((seg * 8 + 4) ^ swz));
    u16* dst = Xt + (size_t)(b * 32 + wv) * KDIM + i8 * 128 + seg * 16;
    *(u32x4*)(dst)     = r0;   // k = seg*16 + 0..7
    *(u32x4*)(dst + 8) = r1;   // k = seg*16 + 8..15
}

// ---------------------------------------------------------------------------
// Kernel 4: bf16 MFMA GEMM, 128x128 tile, BK=64, split-K=4 (r2 config:
// 512 blocks x 256 thr, 2 blocks/CU). XCD-aware flat swizzle: f = m*64 + u,
// u=(n,z) -> all 8 m-blocks sharing a B panel land on XCD u%8.
// XOR-swizzled LDS (swizzle on the GLOBAL source chunk). Atomic epilogue.
// ---------------------------------------------------------------------------
#define BM 128
#define BN 128
#define BK 64
#define ZSPLIT 4
#define KCH (KDIM / ZSPLIT)   // 4096 per split

__global__ __launch_bounds__(256, 2) void gemm_kernel(const u16* __restrict__ A,
                                                      const u16* __restrict__ B,
                                                      float* __restrict__ out) {
    __shared__ __align__(16) u16 As[BM * BK];   // 16KB, [row][chunk^(row&7)]
    __shared__ __align__(16) u16 Bs[BN * BK];   // 16KB
    const int f = blockIdx.x;            // 0..511
    const int m = f >> 6;                // 0..7
    const int u = f & 63;                // (n,z) group -> XCD u%8
    const int n = u & 15;
    const int z = u >> 4;
    const int t    = threadIdx.x;
    const int lane = t & 63;
    const int wave = t >> 6;
    const int wm   = (wave >> 1) * 64;
    const int wn   = (wave & 1) * 64;
    const int quad = lane >> 4;
    const int l16  = lane & 15;
    const int sw   = l16 & 7;            // == row&7 for all fragment rows
    const int o0 = m * BM;
    const int n0 = n * BN;
    const int kb = z * KCH;

    f32x4 acc[4][4] = {};

    // staging: slot (row=32c+rA, chunk c8) holds global chunk c8^(rA&7)
    const int rA = t >> 3;               // 0..31
    const int c8 = t & 7;
    const int csw = (c8 ^ (rA & 7)) * 8;
    const u16* gA = A + (size_t)(o0 + rA) * KDIM + kb + csw;
    const u16* gB = B + (size_t)(n0 + rA) * KDIM + kb + csw;
    u16* lA = As + t * 8;
    u16* lB = Bs + t * 8;

    for (int k0 = 0; k0 < KCH; k0 += BK) {
        #pragma unroll
        for (int c = 0; c < 4; ++c) {
            load_lds_16B(gA + (size_t)c * 32 * KDIM + k0, lA + c * 2048);
            load_lds_16B(gB + (size_t)c * 32 * KDIM + k0, lB + c * 2048);
        }
        __syncthreads();

        #pragma unroll
        for (int ks = 0; ks < 2; ++ks) {
            bf16x8 af[4], bfr[4];
            #pragma unroll
            for (int mt = 0; mt < 4; ++mt) {
                u16x8 bits = *(const u16x8*)(As + (wm + mt * 16 + l16) * BK
                                                + (((ks * 4 + quad) ^ sw) * 8));
                af[mt] = __builtin_bit_cast(bf16x8, bits);
            }
            #pragma unroll
            for (int nt = 0; nt < 4; ++nt) {
                u16x8 bits = *(const u16x8*)(Bs + (wn + nt * 16 + l16) * BK
                                                + (((ks * 4 + quad) ^ sw) * 8));
                bfr[nt] = __builtin_bit_cast(bf16x8, bits);
            }
            #pragma unroll
            for (int mt = 0; mt < 4; ++mt)
                #pragma unroll
                for (int nt = 0; nt < 4; ++nt)
                    acc[mt][nt] = __builtin_amdgcn_mfma_f32_16x16x32_bf16(
                        af[mt], bfr[nt], acc[mt][nt], 0, 0, 0);
        }
        __syncthreads();
    }

    // epilogue: C/D row=quad*4+reg, col=l16; atomic-accumulate at final
    // scattered position: out[(b*16+(o>>6))*2048 + (o&63)*32 + w]
    #pragma unroll
    for (int nt = 0; nt < 4; ++nt) {
        const int nn = n0 + wn + nt * 16 + l16;
        const int bb = nn >> 5, w = nn & 31;
        #pragma unroll
        for (int mt = 0; mt < 4; ++mt) {
            #pragma unroll
            for (int r = 0; r < 4; ++r) {
                const int o = o0 + wm + mt * 16 + quad * 4 + r;
                unsafeAtomicAdd(out + (size_t)(bb * 16 + (o >> 6)) * 2048
                                    + (o & 63) * 32 + w,
                                acc[mt][nt][r]);
            }
        }
    }
}

// ---------------------------------------------------------------------------
// Kernel 5: in-place bias + relu on the accumulated output.
// ---------------------------------------------------------------------------
__global__ __launch_bounds__(256) void finalize_kernel(float* __restrict__ out,
                                                       const float* __restrict__ bias) {
    const int tid = blockIdx.x * 256 + threadIdx.x;
    const int f = tid * 4;
    const int o = ((f >> 11) & 15) * 64 + ((f & 2047) >> 5);
    const float bv = bias[o];
    float4 x = *(float4*)(out + f);
    x.x = fmaxf(x.x + bv, 0.f);
    x.y = fmaxf(x.y + bv, 0.f);
    x.z = fmaxf(x.z + bv, 0.f);
    x.w = fmaxf(x.w + bv, 0.f);
    *(float4*)(out + f) = x;
}

// ---------------------------------------------------------------------------
extern "C" void kernel_launch(void* const* d_in, const int* in_sizes, int n_in,
                              void* d_out, int out_size, void* d_ws, size_t ws_size,
                              hipStream_t stream) {
    const float* f1   = (const float*)d_in[0];   // [1024][1024]
    const float* Wc   = (const float*)d_in[1];   // [1024][1024][16][1]
    const float* bias = (const float*)d_in[2];   // [1024]
    float* out = (float*)d_out;                  // [1024][2048]

    // workspace: idx (64KB) | Wb bf16 (32MB) | Xt bf16 (64MB)  ~= 96MB
    int* idx = (int*)d_ws;
    u16* Wb  = (u16*)((char*)d_ws + 65536);
    u16* Xt  = (u16*)((char*)d_ws + 65536 + (size_t)NDIM * KDIM * 2);

    hipMemsetAsync(d_out, 0, (size_t)NDIM * NCOL * 4, stream);
    topk_kernel<<<NDIM / 4, 256, 0, stream>>>(f1, idx);
    convw_kernel<<<(NDIM * KDIM) / (8 * 256), 256, 0, stream>>>(Wc, Wb);
    buildx_kernel<<<64 * 128, 256, 0, stream>>>(f1, idx, Xt);
    gemm_kernel<<<512, 256, 0, stream>>>(Wb, Xt, out);
    finalize_kernel<<<(NDIM * NCOL) / (4 * 256), 256, 0, stream>>>(out, bias);
}